// Round 8
// baseline (312.885 us; speedup 1.0000x reference)
//
#include <hip/hip_runtime.h>

// ---------------------------------------------------------------------------
// MaskedAutoregressiveFlow (RealNVP coupling) fused kernel for gfx950. R8.
// B=16384 rows, F=64, CTX=128, HID=512, L=8 layers, NB=2 hidden blocks.
//
// R8 = R7 + fp8-e4m3 weight storage (x16 pre-scale), VALU dequant -> bf16
// MFMA. R7 accounting: per-kc CU demand = B 585 cyc (L2, dominant) vs LDS
// ~256+conflicts vs MFMA 64 -> halving B bytes moves the wall to LDS.
// fp8 values are exact in bf16 (3 vs 7 mantissa bits): dequant is
// cvt_pk_f32_fp8 x4 + v_perm_b32 (hi-16 truncation, exact) x4 per frag.
// x16 scale keeps W_out (sigma=0.01) out of e4m3 denormals; epilogue does
// acc*(1/16)+bias via one FMA. b-pipeline now holds raw fp8 (6 VGPRs vs 12).
// ---------------------------------------------------------------------------

typedef short v8s  __attribute__((ext_vector_type(8)));   // 8 x bf16
typedef float v2f  __attribute__((ext_vector_type(2)));
typedef float v4f  __attribute__((ext_vector_type(4)));   // 16x16 acc
typedef float v16f __attribute__((ext_vector_type(16)));  // 32x32 acc

#define BATCH 16384
#define NF    64
#define NCTX  128
#define NL    8

#define PST   68    // LDS p row stride in floats

#define WSCALE    16.0f
#define WSCALE_INV 0.0625f

// packed-weight element offsets (fp8 elements = bytes)
#define WIN_EPL   (160 * 512)                               // 81920 / layer
#define WH_EPB    (512 * 512)                               // 262144 / (layer,block)
#define WOUT_EPL  (512 * 64)                                // 32768 / layer
#define OFF_WIN   ((size_t)0)
#define OFF_WH    ((size_t)(8 * WIN_EPL))                   // 655360
#define OFF_WOUT  (OFF_WH + (size_t)(16 * WH_EPB))          // 4849664
#define TOT_PACK_ELEMS (OFF_WOUT + (size_t)(8 * WOUT_EPL))  // 5111808
#define NEED_WS   (TOT_PACK_ELEMS)                          // 5,111,808 B

// fp32 -> bf16, round-to-nearest-even
__device__ __forceinline__ unsigned short f2b(float f) {
    union { float f; unsigned int u; } x; x.f = f;
    unsigned int r = x.u + 0x7FFFu + ((x.u >> 16) & 1u);
    return (unsigned short)(r >> 16);
}

// LDS h swizzle: element (row, col) at row*512 + ((col>>3) ^ s(row))*8 + (col&7),
// s(row) = (row ^ (row>>2)) & 7.
__device__ __forceinline__ int sw3(int row) { return ((row ^ (row >> 2)) & 7) << 3; }

// 8 x fp8(e4m3) -> 8 x bf16. Exact: every e4m3 value fits bf16's 7-bit
// mantissa, so f32 hi-16 truncation loses nothing.
__device__ __forceinline__ v8s dq8(uint2 r) {
    v2f f0 = __builtin_amdgcn_cvt_pk_f32_fp8(r.x, false);
    v2f f1 = __builtin_amdgcn_cvt_pk_f32_fp8(r.x, true);
    v2f f2 = __builtin_amdgcn_cvt_pk_f32_fp8(r.y, false);
    v2f f3 = __builtin_amdgcn_cvt_pk_f32_fp8(r.y, true);
    union { unsigned int u[4]; v8s s; } o;
    o.u[0] = __builtin_amdgcn_perm(__float_as_uint(f0.y), __float_as_uint(f0.x), 0x07060302u);
    o.u[1] = __builtin_amdgcn_perm(__float_as_uint(f1.y), __float_as_uint(f1.x), 0x07060302u);
    o.u[2] = __builtin_amdgcn_perm(__float_as_uint(f2.y), __float_as_uint(f2.x), 0x07060302u);
    o.u[3] = __builtin_amdgcn_perm(__float_as_uint(f3.y), __float_as_uint(f3.x), 0x07060302u);
    return o.s;
}

// ---------------------------------------------------------------------------
// pack: fp32 -> fp8 e4m3 (x16), DESTINATION-ordered (one 8B store/thread).
// W_in/W_h -> 32x32x16 B-frag order: frag = kc*16 + nt;
//   lane l: k = kc*16 + (l>>5)*8 + j, n = nt*32 + (l&31).
// W_out -> 16x16x32 B-frag order: frag = kc*4 + nt;
//   lane l: k = kc*32 + (l>>4)*8 + j, n = nt*16 + (l&15).
// ---------------------------------------------------------------------------
__global__ void pack_weights_kernel(const float* __restrict__ W_in,
                                    const float* __restrict__ W_h,
                                    const float* __restrict__ W_out,
                                    unsigned char* __restrict__ ws) {
    const int TIN  = 8 * (WIN_EPL / 8);     // 81920
    const int TH   = 16 * (WH_EPB / 8);     // 524288
    const int TOUT = 8 * (WOUT_EPL / 8);    // 32768
    int t = blockIdx.x * blockDim.x + threadIdx.x;
    if (t >= TIN + TH + TOUT) return;
    float v[8];
    if (t < TIN + TH) {
        const float* src; int r;
        if (t < TIN) {
            int i = t / (WIN_EPL / 8); r = t - i * (WIN_EPL / 8);
            src = W_in + (size_t)i * WIN_EPL;
        } else {
            int u = t - TIN; int ij = u >> 15; r = u & 32767;
            src = W_h + (size_t)ij * WH_EPB;
        }
        int frag = r >> 6, lane = r & 63;
        int k0 = (frag >> 4) * 16 + (lane >> 5) * 8;
        int n  = (frag & 15) * 32 + (lane & 31);
#pragma unroll
        for (int j = 0; j < 8; ++j)
            v[j] = src[(size_t)(k0 + j) * 512 + n] * WSCALE;
    } else {
        int u = t - TIN - TH;
        int i = u >> 12, r = u & 4095;
        const float* src = W_out + (size_t)i * WOUT_EPL;
        int frag = r >> 6, lane = r & 63;
        int k0 = (frag >> 2) * 32 + (lane >> 4) * 8;
        int n  = (frag & 3) * 16 + (lane & 15);
#pragma unroll
        for (int j = 0; j < 8; ++j)
            v[j] = src[(size_t)(k0 + j) * 64 + n] * WSCALE;
    }
    uint2 o;
    o.x = 0; o.y = 0;
    o.x = __builtin_amdgcn_cvt_pk_fp8_f32(v[0], v[1], o.x, false);
    o.x = __builtin_amdgcn_cvt_pk_fp8_f32(v[2], v[3], o.x, true);
    o.y = __builtin_amdgcn_cvt_pk_fp8_f32(v[4], v[5], o.y, false);
    o.y = __builtin_amdgcn_cvt_pk_fp8_f32(v[6], v[7], o.y, true);
    *(uint2*)(ws + (size_t)t * 8) = o;
}

// ---------------------------------------------------------------------------
// 32x32x16 stage: h' = relu((A @ W)*ws + bias) for one 32-col strip.
// Wave covers both 32-row tiles; 3-deep raw-fp8 B pipeline (vmcnt(2)).
// ---------------------------------------------------------------------------
template<int KC, bool PACKED>
__device__ __forceinline__ void gemm32(
    const unsigned char* __restrict__ wpk,
    const float* __restrict__ wraw,
    const float* __restrict__ bias,
    const unsigned short* __restrict__ Abuf,
    unsigned short* __restrict__ Obuf,
    int ntile, int lane)
{
    const int l31 = lane & 31, half = lane >> 5;
    v16f acc0, acc1;
#pragma unroll
    for (int r = 0; r < 16; ++r) { acc0[r] = 0.f; acc1[r] = 0.f; }
    const int row0 = l31, row1 = 32 + l31;
    const int ab0 = row0 * 512, ab1 = row1 * 512;
    const int sz0 = sw3(row0), sz1 = sw3(row1);
    const unsigned char* bptr =
        PACKED ? wpk + (size_t)(ntile * 64 + lane) * 8 : (const unsigned char*)0;

    auto loadB = [&](int idx) -> uint2 {
        if (idx >= KC) idx = KC - 1;     // clamped duplicate, harmless
        if constexpr (PACKED) {
            return *(const uint2*)(bptr + (size_t)idx * (16 * 512));
        } else {
            // fallback: gather raw f32, convert to bf16 bits packed in uint2x?
            // (non-packed path converts directly in step via dq-less route)
            int n = ntile * 32 + l31;
            int k0 = idx * 16 + half * 8;
            uint2 rr; unsigned int w[4];
#pragma unroll
            for (int j = 0; j < 4; ++j) {
                unsigned short lo = f2b(wraw[(size_t)(k0 + 2 * j) * 512 + n]);
                unsigned short hi = f2b(wraw[(size_t)(k0 + 2 * j + 1) * 512 + n]);
                w[j] = (unsigned int)lo | ((unsigned int)hi << 16);
            }
            rr.x = w[0]; rr.y = w[1];
            // stash remaining in shared-nothing: fallback handled in step
            // (see stepRaw below) -- we re-load there; simplicity over speed.
            return rr;
        }
    };
    auto step = [&](int kc, uint2 braw) {
        const int cch = (kc * 2 + half) << 3;
        v8s a0 = *(const v8s*)(Abuf + ab0 + (cch ^ sz0));
        v8s a1 = *(const v8s*)(Abuf + ab1 + (cch ^ sz1));
        v8s bf;
        if constexpr (PACKED) {
            bf = dq8(braw);
        } else {
            int n = ntile * 32 + l31;
            int k0 = kc * 16 + half * 8;
#pragma unroll
            for (int j = 0; j < 8; ++j)
                bf[j] = (short)f2b(wraw[(size_t)(k0 + j) * 512 + n]);
        }
        acc0 = __builtin_amdgcn_mfma_f32_32x32x16_bf16(a0, bf, acc0, 0, 0, 0);
        acc1 = __builtin_amdgcn_mfma_f32_32x32x16_bf16(a1, bf, acc1, 0, 0, 0);
    };

    uint2 b0 = loadB(0), b1 = loadB(1), b2 = loadB(2);
    int kc = 0;
#pragma unroll 1
    for (; kc + 2 < KC; kc += 3) {
        step(kc + 0, b0); b0 = loadB(kc + 3);
        step(kc + 1, b1); b1 = loadB(kc + 4);
        step(kc + 2, b2); b2 = loadB(kc + 5);
    }
    if (kc < KC)     step(kc + 0, b0);
    if (kc + 1 < KC) step(kc + 1, b1);

    // epilogue: col = ntile*32 + (lane&31); row = (reg&3)+8*(reg>>2)+4*half
    const float ws = PACKED ? WSCALE_INV : 1.0f;
    const int n = ntile * 32 + l31;
    const float bv = bias[n];
    const int nch = (n >> 3) << 3, nlo = n & 7;
#pragma unroll
    for (int reg = 0; reg < 16; ++reg) {
        int row = (reg & 3) + 8 * (reg >> 2) + 4 * half;
        float v0 = fmaf(acc0[reg], ws, bv); v0 = v0 > 0.f ? v0 : 0.f;
        Obuf[row * 512 + (nch ^ sw3(row)) + nlo] = f2b(v0);
        int rw1 = row + 32;
        float v1 = fmaf(acc1[reg], ws, bv); v1 = v1 > 0.f ? v1 : 0.f;
        Obuf[rw1 * 512 + (nch ^ sw3(rw1)) + nlo] = f2b(v1);
    }
}

__device__ __forceinline__ v4f mfma16(v8s a, v8s b, v4f c) {
    return __builtin_amdgcn_mfma_f32_16x16x32_bf16(a, b, c, 0, 0, 0);
}

// 16x16x32 output stage (G3): p[16x16] = (h @ W_out)*ws + b_out, fp32.
template<bool PACKED>
__device__ __forceinline__ void gemm16_out(
    const unsigned char* __restrict__ wpk,
    const float* __restrict__ wraw,
    const float* __restrict__ bias,
    const unsigned short* __restrict__ Abuf,
    float* __restrict__ Pbuf,
    int mtb, int ntb, int lane)
{
    const int quad = lane >> 4, l15 = lane & 15;
    v4f acc; acc[0] = acc[1] = acc[2] = acc[3] = 0.f;
    const int row = mtb * 16 + l15;
    const int ab = row * 512, sz = sw3(row);
    const unsigned char* bptr =
        PACKED ? wpk + (size_t)(ntb * 64 + lane) * 8 : (const unsigned char*)0;
    constexpr int KC = 16;

    auto loadB = [&](int idx) -> uint2 {
        if (idx >= KC) idx = KC - 1;
        if constexpr (PACKED) {
            return *(const uint2*)(bptr + (size_t)(idx * 4) * 512);
        } else {
            uint2 z; z.x = 0; z.y = 0; return z;
        }
    };
    auto step = [&](int kc, uint2 braw) {
        v8s a = *(const v8s*)(Abuf + ab + ((((kc * 4 + quad) << 3)) ^ sz));
        v8s bf;
        if constexpr (PACKED) {
            bf = dq8(braw);
        } else {
            int k0 = kc * 32 + quad * 8;
            int n  = ntb * 16 + l15;
#pragma unroll
            for (int j = 0; j < 8; ++j)
                bf[j] = (short)f2b(wraw[(size_t)(k0 + j) * 64 + n]);
        }
        acc = mfma16(a, bf, acc);
    };

    uint2 b0 = loadB(0), b1 = loadB(1), b2 = loadB(2);
    int kc = 0;
#pragma unroll 1
    for (; kc + 2 < KC; kc += 3) {
        step(kc + 0, b0); b0 = loadB(kc + 3);
        step(kc + 1, b1); b1 = loadB(kc + 4);
        step(kc + 2, b2); b2 = loadB(kc + 5);
    }
    if (kc < KC)     step(kc + 0, b0);
    if (kc + 1 < KC) step(kc + 1, b1);

    const float ws = PACKED ? WSCALE_INV : 1.0f;
    const int n = ntb * 16 + l15;
    const float bv = bias[n];
#pragma unroll
    for (int r = 0; r < 4; ++r)
        Pbuf[(mtb * 16 + quad * 4 + r) * PST + n] = fmaf(acc[r], ws, bv);
}

template<bool PACKED>
__global__ __launch_bounds__(1024) void flow_kernel(
    const float* __restrict__ inputs,
    const float* __restrict__ ctx,
    const float* __restrict__ W_in,  const float* __restrict__ b_in,
    const float* __restrict__ W_h,   const float* __restrict__ b_h,
    const float* __restrict__ W_out, const float* __restrict__ b_out,
    const int*   __restrict__ perms,
    const unsigned char* __restrict__ wpk,
    float* __restrict__ out)
{
    __shared__ __align__(16) unsigned short hbuf0[64 * 512];  // 65,536 B
    __shared__ __align__(16) unsigned short hbuf1[64 * 512];  // 65,536 B
    __shared__ __align__(16) float xbuf[64 * NF];             // 16,384 B
    __shared__ int permsh[NF];

    float* pbuf    = (float*)hbuf0;   // p (64 x 64 fp32, stride PST) after G3
    float* scratch = (float*)hbuf1;   // permutation scratch

    const int tid  = threadIdx.x;
    const int wave = tid >> 6;        // 0..15
    const int lane = tid & 63;
    const int trow = tid >> 4;        // 0..63 : row owned in elementwise phases
    const int tq   = tid & 15;        // 0..15 : 1/16th of that row
    const int row0 = blockIdx.x * 64;

    // ---- load + clip x tile (1024 float4 / 1024 threads = 1 each)
    {
        const float4* in4 = (const float4*)(inputs + (size_t)row0 * NF);
        float4 v = in4[tid];
        v.x = fminf(fmaxf(v.x, -1.f), 1.f);
        v.y = fminf(fmaxf(v.y, -1.f), 1.f);
        v.z = fminf(fmaxf(v.z, -1.f), 1.f);
        v.w = fminf(fmaxf(v.w, -1.f), 1.f);
        ((float4*)xbuf)[tid] = v;
    }
    float ld_acc = 0.f;
    __syncthreads();

#pragma unroll 1
    for (int i = 0; i < NL; ++i) {
        const int par = i & 1;        // t_idx parity (even layer -> even cols)
        const int idp = par ^ 1;      // id_idx parity

        // ---- stage A0 = [id_split(32) | context(128)] bf16 into hbuf0
        {
            const int s3 = sw3(trow);
            unsigned short* hrow = hbuf0 + trow * 512;

            const float* crow = ctx + (size_t)(row0 + trow) * NCTX + tq * 8;
            float4 f0 = ((const float4*)crow)[0];
            float4 f1 = ((const float4*)crow)[1];
            v8s ck;
            ck[0] = (short)f2b(f0.x); ck[1] = (short)f2b(f0.y);
            ck[2] = (short)f2b(f0.z); ck[3] = (short)f2b(f0.w);
            ck[4] = (short)f2b(f1.x); ck[5] = (short)f2b(f1.y);
            ck[6] = (short)f2b(f1.z); ck[7] = (short)f2b(f1.w);
            *(v8s*)(hrow + (((4 + tq) << 3) ^ s3)) = ck;

            if (tq < 4) {
                v8s idv;
#pragma unroll
                for (int j = 0; j < 8; ++j)
                    idv[j] = (short)f2b(xbuf[trow * NF + 2 * (tq * 8 + j) + idp]);
                *(v8s*)(hrow + ((tq << 3) ^ s3)) = idv;
            }
        }
        __syncthreads();

        // ---- G0: h = relu([id|ctx] @ W_in + b_in)   (K=160, N=512)
        gemm32<10, PACKED>(
            PACKED ? wpk + OFF_WIN + (size_t)i * WIN_EPL : (const unsigned char*)0,
            W_in + (size_t)i * WIN_EPL, b_in + i * 512,
            hbuf0, hbuf1, wave, lane);
        __syncthreads();
        // ---- G1
        gemm32<32, PACKED>(
            PACKED ? wpk + OFF_WH + (size_t)(i * 2 + 0) * WH_EPB : (const unsigned char*)0,
            W_h + (size_t)(i * 2 + 0) * WH_EPB, b_h + (i * 2 + 0) * 512,
            hbuf1, hbuf0, wave, lane);
        __syncthreads();
        // ---- G2
        gemm32<32, PACKED>(
            PACKED ? wpk + OFF_WH + (size_t)(i * 2 + 1) * WH_EPB : (const unsigned char*)0,
            W_h + (size_t)(i * 2 + 1) * WH_EPB, b_h + (i * 2 + 1) * 512,
            hbuf0, hbuf1, wave, lane);
        __syncthreads();
        // ---- G3: p = h @ W_out + b_out  (N=64, fp32 into pbuf)
        //      16 waves x 1 tile: mtb = wave>>2, ntb = wave&3
        gemm16_out<PACKED>(
            PACKED ? wpk + OFF_WOUT + (size_t)i * WOUT_EPL : (const unsigned char*)0,
            W_out + (size_t)i * WOUT_EPL, b_out + i * 64,
            hbuf1, pbuf, wave >> 2, wave & 3, lane);
        __syncthreads();

        // ---- coupling: shift = p[:, :32]; scale = sigmoid(p[:,32:]+2)+1e-3
        {
#pragma unroll
            for (int j = 0; j < 2; ++j) {
                int sc = tq * 2 + j;
                float shiftv = pbuf[trow * PST + sc];
                float z = pbuf[trow * PST + 32 + sc] + 2.0f;
                float s = 1.0f / (1.0f + __expf(-z)) + 0.001f;
                int tc = 2 * sc + par;
                xbuf[trow * NF + tc] = xbuf[trow * NF + tc] * s + shiftv;
                ld_acc += __logf(s);
            }
        }
        __syncthreads();

        // ---- permutation: x = x[:, perm[i]]
        if (i < NL - 1) {
            ((float4*)scratch)[tid] = ((float4*)xbuf)[tid];
            if (tid < NF) permsh[tid] = perms[i * NF + tid];
            __syncthreads();
#pragma unroll
            for (int j = 0; j < 4; ++j) {
                int c = tq * 4 + j;
                xbuf[trow * NF + c] = scratch[trow * NF + permsh[c]];
            }
            __syncthreads();
        }
    }

    // ---- outputs: clip(x) then logdet
    {
        float4 v = ((float4*)xbuf)[tid];
        v.x = fminf(fmaxf(v.x, -1.f), 1.f);
        v.y = fminf(fmaxf(v.y, -1.f), 1.f);
        v.z = fminf(fmaxf(v.z, -1.f), 1.f);
        v.w = fminf(fmaxf(v.w, -1.f), 1.f);
        ((float4*)(out + (size_t)row0 * NF))[tid] = v;
    }
    // reduce 16 partials per row (lanes 16r..16r+15 contiguous in a wave)
    ld_acc += __shfl_down(ld_acc, 1);
    ld_acc += __shfl_down(ld_acc, 2);
    ld_acc += __shfl_down(ld_acc, 4);
    ld_acc += __shfl_down(ld_acc, 8);
    if (tq == 0) out[(size_t)BATCH * NF + row0 + trow] = ld_acc;
}

extern "C" void kernel_launch(void* const* d_in, const int* in_sizes, int n_in,
                              void* d_out, int out_size, void* d_ws, size_t ws_size,
                              hipStream_t stream) {
    const float* inputs  = (const float*)d_in[0];
    const float* context = (const float*)d_in[1];
    const float* W_in    = (const float*)d_in[2];
    const float* b_in    = (const float*)d_in[3];
    const float* W_h     = (const float*)d_in[4];
    const float* b_h     = (const float*)d_in[5];
    const float* W_out   = (const float*)d_in[6];
    const float* b_out   = (const float*)d_in[7];
    const int*   perms   = (const int*)d_in[8];
    float* out = (float*)d_out;

    if (ws_size >= (size_t)NEED_WS) {
        unsigned char* ws = (unsigned char*)d_ws;
        const int total_threads = (int)(TOT_PACK_ELEMS / 8);    // 638976
        pack_weights_kernel<<<(total_threads + 255) / 256, 256, 0, stream>>>(
            W_in, W_h, W_out, ws);
        flow_kernel<true><<<256, 1024, 0, stream>>>(
            inputs, context, W_in, b_in, W_h, b_h, W_out, b_out, perms, ws, out);
    } else {
        flow_kernel<false><<<256, 1024, 0, stream>>>(
            inputs, context, W_in, b_in, W_h, b_h, W_out, b_out, perms,
            (const unsigned char*)0, out);
    }
}

// Round 10
// 272.774 us; speedup vs baseline: 1.1470x; 1.1470x over previous
//
#include <hip/hip_runtime.h>

// ---------------------------------------------------------------------------
// MaskedAutoregressiveFlow (RealNVP coupling) fused kernel for gfx950. R10.
// B=16384 rows, F=64, CTX=128, HID=512, L=8 layers, NB=2 hidden blocks.
//
// R10 = R9 (full fp8 datapath) with the cvt_pk_fp8 hi-bit as a template
// parameter (it must be an immediate in the instruction encoding).
//
// R9 theory (untested due to compile error): native
// v_mfma_f32_32x32x16_fp8_fp8 removes R8's VALU dequant AND halves both
// remaining walls: B-L2 585->292 cyc/kc, A-LDS 385->~190 (8B frags).
// MFMA rate = bf16 rate (m35) so the MFMA floor (~70us) is unchanged.
//  - h stored fp8 in LDS, row stride 520 B (2-dword bank skew, 2-way = free).
//  - weights pre-scaled x16 into e4m3; epilogue folds 1/16 into bias FMA.
//  - identity path (xbuf) stays fp32: fp8 error only enters via shift/scale.
//  - D=4 B prefetch pipeline: 16 waves x 2KB outstanding = 32KB/CU.
// ---------------------------------------------------------------------------

typedef float v4f  __attribute__((ext_vector_type(4)));
typedef float v16f __attribute__((ext_vector_type(16)));
typedef unsigned char uchar;
typedef unsigned long long ull;

#define BATCH 16384
#define NF    64
#define NCTX  128
#define NL    8

#define RS    520   // fp8 h row stride in bytes
#define PST   68    // LDS p row stride in floats

#define WSCALE     16.0f
#define WSCALE_INV 0.0625f

// packed-weight element offsets (fp8 elements = bytes)
#define WIN_EPL   (160 * 512)                               // 81920 / layer
#define WH_EPB    (512 * 512)                               // 262144 / (layer,block)
#define WOUT_EPL  (512 * 64)                                // 32768 / layer
#define OFF_WIN   ((size_t)0)
#define OFF_WH    ((size_t)(8 * WIN_EPL))                   // 655360
#define OFF_WOUT  (OFF_WH + (size_t)(16 * WH_EPB))          // 4849664
#define TOT_PACK_ELEMS (OFF_WOUT + (size_t)(8 * WOUT_EPL))  // 5111808
#define NEED_WS   (TOT_PACK_ELEMS)                          // 5,111,808 B

template<bool HI>
__device__ __forceinline__ unsigned int pk2(float a, float b, unsigned int old) {
    return __builtin_amdgcn_cvt_pk_fp8_f32(a, b, old, HI);
}
__device__ __forceinline__ uchar q8(float v) {
    return (uchar)(__builtin_amdgcn_cvt_pk_fp8_f32(v, v, 0u, false) & 0xffu);
}

// ---------------------------------------------------------------------------
// pack: fp32 -> fp8 e4m3 (x16), DESTINATION-ordered (one 8B store/thread).
// W_in/W_h -> 32x32x16 B-frag order: frag = kc*16 + nt;
//   lane l: k = kc*16 + (l>>5)*8 + j, n = nt*32 + (l&31).
// W_out -> 16x16x32 B-frag order: frag = kc*4 + nt;
//   lane l: k = kc*32 + (l>>4)*8 + j, n = nt*16 + (l&15).
// ---------------------------------------------------------------------------
__global__ void pack_weights_kernel(const float* __restrict__ W_in,
                                    const float* __restrict__ W_h,
                                    const float* __restrict__ W_out,
                                    unsigned char* __restrict__ ws) {
    const int TIN  = 8 * (WIN_EPL / 8);     // 81920
    const int TH   = 16 * (WH_EPB / 8);     // 524288
    const int TOUT = 8 * (WOUT_EPL / 8);    // 32768
    int t = blockIdx.x * blockDim.x + threadIdx.x;
    if (t >= TIN + TH + TOUT) return;
    float v[8];
    if (t < TIN + TH) {
        const float* src; int r;
        if (t < TIN) {
            int i = t / (WIN_EPL / 8); r = t - i * (WIN_EPL / 8);
            src = W_in + (size_t)i * WIN_EPL;
        } else {
            int u = t - TIN; int ij = u >> 15; r = u & 32767;
            src = W_h + (size_t)ij * WH_EPB;
        }
        int frag = r >> 6, lane = r & 63;
        int k0 = (frag >> 4) * 16 + (lane >> 5) * 8;
        int n  = (frag & 15) * 32 + (lane & 31);
#pragma unroll
        for (int j = 0; j < 8; ++j)
            v[j] = src[(size_t)(k0 + j) * 512 + n] * WSCALE;
    } else {
        int u = t - TIN - TH;
        int i = u >> 12, r = u & 4095;
        const float* src = W_out + (size_t)i * WOUT_EPL;
        int frag = r >> 6, lane = r & 63;
        int k0 = (frag >> 2) * 32 + (lane >> 4) * 8;
        int n  = (frag & 3) * 16 + (lane & 15);
#pragma unroll
        for (int j = 0; j < 8; ++j)
            v[j] = src[(size_t)(k0 + j) * 64 + n] * WSCALE;
    }
    uint2 o;
    o.x = pk2<false>(v[0], v[1], 0u);
    o.x = pk2<true >(v[2], v[3], o.x);
    o.y = pk2<false>(v[4], v[5], 0u);
    o.y = pk2<true >(v[6], v[7], o.y);
    *(uint2*)(ws + (size_t)t * 8) = o;
}

// ---------------------------------------------------------------------------
// 32x32x16 fp8 stage: h' = relu((A @ W)*1/16 + bias) for one 32-col strip.
// Wave covers both 32-row tiles; D=4 B pipeline (vmcnt(3) steady state).
// ---------------------------------------------------------------------------
template<int KC, bool PACKED>
__device__ __forceinline__ void gemm32(
    const uchar* __restrict__ wpk,
    const float* __restrict__ wraw,
    const float* __restrict__ bias,
    const uchar* __restrict__ Abuf,
    uchar* __restrict__ Obuf,
    int ntile, int lane)
{
    const int l31 = lane & 31, half = lane >> 5;
    v16f acc0, acc1;
#pragma unroll
    for (int r = 0; r < 16; ++r) { acc0[r] = 0.f; acc1[r] = 0.f; }
    const uchar* a0p = Abuf + l31 * RS + half * 8;
    const uchar* a1p = a0p + 32 * RS;
    const uchar* bptr =
        PACKED ? wpk + (size_t)(ntile * 64 + lane) * 8 : (const uchar*)0;

    auto loadB = [&](int idx) -> ull {
        if constexpr (PACKED) {
            return *(const ull*)(bptr + (size_t)idx * 8192);   // 16 frags x 512B
        } else {
            int n  = ntile * 32 + l31;
            int k0 = idx * 16 + half * 8;
            unsigned int lo, hi;
            lo = pk2<false>(wraw[(size_t)(k0 + 0) * 512 + n] * WSCALE,
                            wraw[(size_t)(k0 + 1) * 512 + n] * WSCALE, 0u);
            lo = pk2<true >(wraw[(size_t)(k0 + 2) * 512 + n] * WSCALE,
                            wraw[(size_t)(k0 + 3) * 512 + n] * WSCALE, lo);
            hi = pk2<false>(wraw[(size_t)(k0 + 4) * 512 + n] * WSCALE,
                            wraw[(size_t)(k0 + 5) * 512 + n] * WSCALE, 0u);
            hi = pk2<true >(wraw[(size_t)(k0 + 6) * 512 + n] * WSCALE,
                            wraw[(size_t)(k0 + 7) * 512 + n] * WSCALE, hi);
            return ((ull)hi << 32) | (ull)lo;
        }
    };
    auto step = [&](int kc, ull bb) {
        ull a0 = *(const ull*)(a0p + kc * 16);
        ull a1 = *(const ull*)(a1p + kc * 16);
        acc0 = __builtin_amdgcn_mfma_f32_32x32x16_fp8_fp8(
                   (long)a0, (long)bb, acc0, 0, 0, 0);
        acc1 = __builtin_amdgcn_mfma_f32_32x32x16_fp8_fp8(
                   (long)a1, (long)bb, acc1, 0, 0, 0);
    };

    ull b0 = loadB(0), b1 = loadB(1), b2 = loadB(2), b3 = loadB(3);
    int kc = 0;
#pragma unroll 1
    for (; kc + 3 < KC; kc += 4) {
        step(kc + 0, b0); if (kc + 4 < KC) b0 = loadB(kc + 4);
        step(kc + 1, b1); if (kc + 5 < KC) b1 = loadB(kc + 5);
        step(kc + 2, b2); if (kc + 6 < KC) b2 = loadB(kc + 6);
        step(kc + 3, b3); if (kc + 7 < KC) b3 = loadB(kc + 7);
    }
    if (kc     < KC) step(kc,     b0);
    if (kc + 1 < KC) step(kc + 1, b1);
    if (kc + 2 < KC) step(kc + 2, b2);

    // epilogue: col = ntile*32 + l31; row = (reg&3)+8*(reg>>2)+4*half
    const int n = ntile * 32 + l31;
    const float bv = bias[n];
#pragma unroll
    for (int reg = 0; reg < 16; ++reg) {
        int row = (reg & 3) + 8 * (reg >> 2) + 4 * half;
        float v0 = fmaf(acc0[reg], WSCALE_INV, bv);
        v0 = fmaxf(v0, 0.f);
        Obuf[row * RS + n] = q8(v0);
        float v1 = fmaf(acc1[reg], WSCALE_INV, bv);
        v1 = fmaxf(v1, 0.f);
        Obuf[(row + 32) * RS + n] = q8(v1);
    }
}

// 16x16x32 fp8 output stage (G3): p[16x16] = (h @ W_out)*1/16 + b_out, fp32.
template<bool PACKED>
__device__ __forceinline__ void gemm16_out(
    const uchar* __restrict__ wpk,
    const float* __restrict__ wraw,
    const float* __restrict__ bias,
    const uchar* __restrict__ Abuf,
    float* __restrict__ Pbuf,
    int mtb, int ntb, int lane)
{
    const int quad = lane >> 4, l15 = lane & 15;
    v4f acc; acc[0] = acc[1] = acc[2] = acc[3] = 0.f;
    const uchar* ap = Abuf + (mtb * 16 + l15) * RS + quad * 8;
    const uchar* bptr =
        PACKED ? wpk + (size_t)(ntb * 64 + lane) * 8 : (const uchar*)0;
    constexpr int KC = 16;

    auto loadB = [&](int idx) -> ull {
        if constexpr (PACKED) {
            return *(const ull*)(bptr + (size_t)idx * 2048);   // 4 frags x 512B
        } else {
            int n  = ntb * 16 + l15;
            int k0 = idx * 32 + quad * 8;
            unsigned int lo, hi;
            lo = pk2<false>(wraw[(size_t)(k0 + 0) * 64 + n] * WSCALE,
                            wraw[(size_t)(k0 + 1) * 64 + n] * WSCALE, 0u);
            lo = pk2<true >(wraw[(size_t)(k0 + 2) * 64 + n] * WSCALE,
                            wraw[(size_t)(k0 + 3) * 64 + n] * WSCALE, lo);
            hi = pk2<false>(wraw[(size_t)(k0 + 4) * 64 + n] * WSCALE,
                            wraw[(size_t)(k0 + 5) * 64 + n] * WSCALE, 0u);
            hi = pk2<true >(wraw[(size_t)(k0 + 6) * 64 + n] * WSCALE,
                            wraw[(size_t)(k0 + 7) * 64 + n] * WSCALE, hi);
            return ((ull)hi << 32) | (ull)lo;
        }
    };
    auto step = [&](int kc, ull bb) {
        ull a = *(const ull*)(ap + kc * 32);
        acc = __builtin_amdgcn_mfma_f32_16x16x32_fp8_fp8(
                  (long)a, (long)bb, acc, 0, 0, 0);
    };

    ull b0 = loadB(0), b1 = loadB(1), b2 = loadB(2), b3 = loadB(3);
    int kc = 0;
#pragma unroll 1
    for (; kc + 3 < KC; kc += 4) {
        step(kc + 0, b0); if (kc + 4 < KC) b0 = loadB(kc + 4);
        step(kc + 1, b1); if (kc + 5 < KC) b1 = loadB(kc + 5);
        step(kc + 2, b2); if (kc + 6 < KC) b2 = loadB(kc + 6);
        step(kc + 3, b3); if (kc + 7 < KC) b3 = loadB(kc + 7);
    }
    if (kc     < KC) step(kc,     b0);
    if (kc + 1 < KC) step(kc + 1, b1);
    if (kc + 2 < KC) step(kc + 2, b2);

    const int n = ntb * 16 + l15;
    const float bv = bias[n];
#pragma unroll
    for (int r = 0; r < 4; ++r)
        Pbuf[(mtb * 16 + quad * 4 + r) * PST + n] = fmaf(acc[r], WSCALE_INV, bv);
}

template<bool PACKED>
__global__ __launch_bounds__(1024) void flow_kernel(
    const float* __restrict__ inputs,
    const float* __restrict__ ctx,
    const float* __restrict__ W_in,  const float* __restrict__ b_in,
    const float* __restrict__ W_h,   const float* __restrict__ b_h,
    const float* __restrict__ W_out, const float* __restrict__ b_out,
    const int*   __restrict__ perms,
    const uchar* __restrict__ wpk,
    float* __restrict__ out)
{
    __shared__ __align__(16) uchar hbuf0[64 * RS];            // 33,280 B
    __shared__ __align__(16) uchar hbuf1[64 * RS];            // 33,280 B
    __shared__ __align__(16) float xbuf[64 * NF];             // 16,384 B
    __shared__ int permsh[NF];

    float* pbuf    = (float*)hbuf0;   // p (64 x 64 fp32, stride PST) after G3
    float* scratch = (float*)hbuf1;   // permutation scratch (16 KB <= 33 KB)

    const int tid  = threadIdx.x;
    const int wave = tid >> 6;        // 0..15
    const int lane = tid & 63;
    const int trow = tid >> 4;        // 0..63 : row owned in elementwise phases
    const int tq   = tid & 15;        // 0..15 : 1/16th of that row
    const int row0 = blockIdx.x * 64;

    // ---- load + clip x tile (1024 float4 / 1024 threads = 1 each)
    {
        const float4* in4 = (const float4*)(inputs + (size_t)row0 * NF);
        float4 v = in4[tid];
        v.x = fminf(fmaxf(v.x, -1.f), 1.f);
        v.y = fminf(fmaxf(v.y, -1.f), 1.f);
        v.z = fminf(fmaxf(v.z, -1.f), 1.f);
        v.w = fminf(fmaxf(v.w, -1.f), 1.f);
        ((float4*)xbuf)[tid] = v;
    }
    float ld_acc = 0.f;
    __syncthreads();

#pragma unroll 1
    for (int i = 0; i < NL; ++i) {
        const int par = i & 1;        // t_idx parity (even layer -> even cols)
        const int idp = par ^ 1;      // id_idx parity

        // ---- stage A0 = [id_split(32) | context(128)] fp8 into hbuf0
        //      16 threads/row: each converts 8 ctx cols -> one uint2 store;
        //      threads 0-3 also convert 8 id cols.
        {
            uchar* hrow = hbuf0 + trow * RS;
            const float* crow = ctx + (size_t)(row0 + trow) * NCTX + tq * 8;
            float4 f0 = ((const float4*)crow)[0];
            float4 f1 = ((const float4*)crow)[1];
            uint2 ck;
            ck.x = pk2<false>(f0.x, f0.y, 0u);
            ck.x = pk2<true >(f0.z, f0.w, ck.x);
            ck.y = pk2<false>(f1.x, f1.y, 0u);
            ck.y = pk2<true >(f1.z, f1.w, ck.y);
            *(uint2*)(hrow + 32 + tq * 8) = ck;

            if (tq < 4) {
                const float* xr = xbuf + trow * NF + idp;
                uint2 idv;
                idv.x = pk2<false>(xr[2 * (tq * 8 + 0)], xr[2 * (tq * 8 + 1)], 0u);
                idv.x = pk2<true >(xr[2 * (tq * 8 + 2)], xr[2 * (tq * 8 + 3)], idv.x);
                idv.y = pk2<false>(xr[2 * (tq * 8 + 4)], xr[2 * (tq * 8 + 5)], 0u);
                idv.y = pk2<true >(xr[2 * (tq * 8 + 6)], xr[2 * (tq * 8 + 7)], idv.y);
                *(uint2*)(hrow + tq * 8) = idv;
            }
        }
        __syncthreads();

        // ---- G0: h = relu([id|ctx] @ W_in + b_in)   (K=160, N=512)
        gemm32<10, PACKED>(
            PACKED ? wpk + OFF_WIN + (size_t)i * WIN_EPL : (const uchar*)0,
            W_in + (size_t)i * WIN_EPL, b_in + i * 512,
            hbuf0, hbuf1, wave, lane);
        __syncthreads();
        // ---- G1
        gemm32<32, PACKED>(
            PACKED ? wpk + OFF_WH + (size_t)(i * 2 + 0) * WH_EPB : (const uchar*)0,
            W_h + (size_t)(i * 2 + 0) * WH_EPB, b_h + (i * 2 + 0) * 512,
            hbuf1, hbuf0, wave, lane);
        __syncthreads();
        // ---- G2
        gemm32<32, PACKED>(
            PACKED ? wpk + OFF_WH + (size_t)(i * 2 + 1) * WH_EPB : (const uchar*)0,
            W_h + (size_t)(i * 2 + 1) * WH_EPB, b_h + (i * 2 + 1) * 512,
            hbuf0, hbuf1, wave, lane);
        __syncthreads();
        // ---- G3: p = h @ W_out + b_out  (N=64, fp32 into pbuf)
        //      16 waves x 1 tile: mtb = wave>>2, ntb = wave&3
        gemm16_out<PACKED>(
            PACKED ? wpk + OFF_WOUT + (size_t)i * WOUT_EPL : (const uchar*)0,
            W_out + (size_t)i * WOUT_EPL, b_out + i * 64,
            hbuf1, pbuf, wave >> 2, wave & 3, lane);
        __syncthreads();

        // ---- coupling: shift = p[:, :32]; scale = sigmoid(p[:,32:]+2)+1e-3
        {
#pragma unroll
            for (int j = 0; j < 2; ++j) {
                int sc = tq * 2 + j;
                float shiftv = pbuf[trow * PST + sc];
                float z = pbuf[trow * PST + 32 + sc] + 2.0f;
                float s = 1.0f / (1.0f + __expf(-z)) + 0.001f;
                int tc = 2 * sc + par;
                xbuf[trow * NF + tc] = xbuf[trow * NF + tc] * s + shiftv;
                ld_acc += __logf(s);
            }
        }
        __syncthreads();

        // ---- permutation: x = x[:, perm[i]]
        if (i < NL - 1) {
            ((float4*)scratch)[tid] = ((float4*)xbuf)[tid];
            if (tid < NF) permsh[tid] = perms[i * NF + tid];
            __syncthreads();
#pragma unroll
            for (int j = 0; j < 4; ++j) {
                int c = tq * 4 + j;
                xbuf[trow * NF + c] = scratch[trow * NF + permsh[c]];
            }
            __syncthreads();
        }
    }

    // ---- outputs: clip(x) then logdet
    {
        float4 v = ((float4*)xbuf)[tid];
        v.x = fminf(fmaxf(v.x, -1.f), 1.f);
        v.y = fminf(fmaxf(v.y, -1.f), 1.f);
        v.z = fminf(fmaxf(v.z, -1.f), 1.f);
        v.w = fminf(fmaxf(v.w, -1.f), 1.f);
        ((float4*)(out + (size_t)row0 * NF))[tid] = v;
    }
    // reduce 16 partials per row (lanes 16r..16r+15 contiguous in a wave)
    ld_acc += __shfl_down(ld_acc, 1);
    ld_acc += __shfl_down(ld_acc, 2);
    ld_acc += __shfl_down(ld_acc, 4);
    ld_acc += __shfl_down(ld_acc, 8);
    if (tq == 0) out[(size_t)BATCH * NF + row0 + trow] = ld_acc;
}

extern "C" void kernel_launch(void* const* d_in, const int* in_sizes, int n_in,
                              void* d_out, int out_size, void* d_ws, size_t ws_size,
                              hipStream_t stream) {
    const float* inputs  = (const float*)d_in[0];
    const float* context = (const float*)d_in[1];
    const float* W_in    = (const float*)d_in[2];
    const float* b_in    = (const float*)d_in[3];
    const float* W_h     = (const float*)d_in[4];
    const float* b_h     = (const float*)d_in[5];
    const float* W_out   = (const float*)d_in[6];
    const float* b_out   = (const float*)d_in[7];
    const int*   perms   = (const int*)d_in[8];
    float* out = (float*)d_out;

    if (ws_size >= (size_t)NEED_WS) {
        uchar* ws = (uchar*)d_ws;
        const int total_threads = (int)(TOT_PACK_ELEMS / 8);    // 638976
        pack_weights_kernel<<<(total_threads + 255) / 256, 256, 0, stream>>>(
            W_in, W_h, W_out, ws);
        flow_kernel<true><<<256, 1024, 0, stream>>>(
            inputs, context, W_in, b_in, W_h, b_h, W_out, b_out, perms, ws, out);
    } else {
        flow_kernel<false><<<256, 1024, 0, stream>>>(
            inputs, context, W_in, b_in, W_h, b_h, W_out, b_out, perms,
            (const uchar*)0, out);
    }
}